// Round 4
// baseline (126.935 us; speedup 1.0000x reference)
//
#include <hip/hip_runtime.h>
#include <math.h>

typedef __attribute__((ext_vector_type(8))) short short8;  // 8 bf16 = 4 VGPRs
typedef __attribute__((ext_vector_type(4))) float f32x4;

// Problem dims
#define D0n 8
#define D1n 12
#define D2n 6
#define Ln 2000
#define An 21
#define KPn 8
#define Un 48
#define PPn 1993              // L - k + 1
#define Bn 576                // D0*D1*D2
#define S_SIZE 4608           // (D0*D1) * U
#define R_SIZE 8064

// Conv tiling: 256 threads = 4 waves, each wave a 32-position x 48-u tile.
#define BPn 128               // positions per block
#define NPT 16                // ceil(1993/128)
#define XROWS 136             // BPn + 8 halo
#define XS_BYTES (XROWS * 64) // 8704: row = 32 bf16 (21 data + 11 zero)
#define RED_OFF XS_BYTES

// XOR swizzle: moves 16B slots within each 512B (8-row) group; bijective,
// preserves 16B alignment. Writer and reader both apply it.
__device__ __forceinline__ int swz(int b) { return b ^ ((b >> 2) & 0x70); }

__device__ __forceinline__ unsigned int fkey(float f) {
    unsigned int u = __float_as_uint(f);
    return (u & 0x80000000u) ? ~u : (u | 0x80000000u);
}
__device__ __forceinline__ float funkey(unsigned int k) {
    return __uint_as_float((k & 0x80000000u) ? (k ^ 0x80000000u) : ~k);
}
__device__ __forceinline__ unsigned short f2bf(float v) {
    unsigned int b = __float_as_uint(v);
    return (unsigned short)((b + 0x7FFFu + ((b >> 16) & 1u)) >> 16);  // RNE
}

// Kernel 1: zero S-keys; R = log(max(softmax(P_logit)/Q, eps)) -> fp32 to
// d_out + bf16 alphabet-padded(21->32) pre-swizzled copy to ws (row = q*48+u,
// 64B rows) which k_conv loads straight into registers.
__global__ void k_profile(const float* __restrict__ P_logit,
                          const float* __restrict__ Q,
                          float* __restrict__ Rout,
                          unsigned short* __restrict__ Rb,
                          unsigned int* __restrict__ Skey) {
    int t = blockIdx.x * blockDim.x + threadIdx.x;
    if (t < S_SIZE) Skey[t] = 0u;  // key 0 == identity for monotone-uint max
    if (t >= KPn * Un) return;
    int kp = t / Un, u = t % Un;
    const float* pl = P_logit + kp * (An * Un) + u;
    float v[An];
    float m = -INFINITY;
#pragma unroll
    for (int a = 0; a < An; ++a) { v[a] = pl[a * Un]; m = fmaxf(m, v[a]); }
    float s = 0.f;
#pragma unroll
    for (int a = 0; a < An; ++a) { v[a] = expf(v[a] - m); s += v[a]; }
    float inv = 1.f / s;
    int rowp = kp * Un + u;
#pragma unroll
    for (int a = 0; a < An; ++a) {
        float r = logf(fmaxf(v[a] * inv / Q[a], 1e-6f));
        Rout[(kp * An + a) * Un + u] = r;
        Rb[swz(rowp * 64 + a * 2) >> 1] = f2bf(r);
    }
#pragma unroll
    for (int a = An; a < 32; ++a) Rb[swz(rowp * 64 + a * 2) >> 1] = 0;
}

// Kernel 2: Z[b,p,u] = sum_q sum_a X[b,p+q,a]*R[q*21+a,u], bf16 MFMA.
// B (R) lives entirely in registers (24 frags = 96 VGPR), identical for all
// waves; LDS holds only the X tile. 4 waves x 32 positions each.
__global__ __launch_bounds__(256, 3) void k_conv(
        const float* __restrict__ X,
        const unsigned short* __restrict__ Rb,
        float* __restrict__ Z,
        unsigned int* __restrict__ Skey) {
    __shared__ char smem[XS_BYTES + 4 * Un * 4];
    const int b = blockIdx.y;
    const int p0 = blockIdx.x * BPn;
    const int t = threadIdx.x;
    const int w = t >> 6;        // wave 0..3
    const int l = t & 63;
    const int lr = l & 15;       // fragment lane row/col
    const int ls = l >> 4;       // k-subchunk / C-row group
    const int pw = w * 32;

    // B-fragments from ws (bf16+padded+swizzled): 24 coalesced 16B loads,
    // L2-broadcast across all blocks.
    short8 bf[KPn][3];
#pragma unroll
    for (int q = 0; q < KPn; ++q)
#pragma unroll
        for (int nt = 0; nt < 3; ++nt) {
            int rowp = q * Un + nt * 16 + lr;
            bf[q][nt] = *(const short8*)((const char*)Rb +
                                         swz(rowp * 64 + ls * 16));
        }

    // Stage X: zero-fill slab (b128), then overwrite the 21 valid bf16 per
    // row as packed pairs.
    {
        uint4 z4 = {0u, 0u, 0u, 0u};
        uint4* xs = (uint4*)smem;
#pragma unroll
        for (int i = 0; i < XS_BYTES / 16 / 256 + 1; ++i) {
            int idx = t + i * 256;
            if (idx < XS_BYTES / 16) xs[idx] = z4;
        }
    }
    __syncthreads();
    {
        const int rows_avail = min(XROWS, Ln - p0);
        const int npair = rows_avail * 11;  // 11 bf16-pairs per row
        const float* Xb = X + ((size_t)b * Ln + p0) * An;
        for (int j = t; j < npair; j += 256) {
            int row = j / 11, jj = j - row * 11;
            int a = jj * 2;
            float v0 = Xb[row * An + a];
            float v1 = (a + 1 < An) ? Xb[row * An + a + 1] : 0.f;
            unsigned int pk = (unsigned int)f2bf(v0) |
                              ((unsigned int)f2bf(v1) << 16);
            *(unsigned int*)(smem + swz(row * 64 + a * 2)) = pk;
        }
    }
    __syncthreads();

    f32x4 acc[2][3];
#pragma unroll
    for (int m = 0; m < 2; ++m)
#pragma unroll
        for (int n = 0; n < 3; ++n) acc[m][n] = (f32x4){0.f, 0.f, 0.f, 0.f};

#pragma unroll
    for (int q = 0; q < KPn; ++q) {
        const int ar = pw + q + lr;
        short8 a0 = *(const short8*)(smem + swz(ar * 64 + ls * 16));
        short8 a1 = *(const short8*)(smem + swz((ar + 16) * 64 + ls * 16));
        acc[0][0] = __builtin_amdgcn_mfma_f32_16x16x32_bf16(a0, bf[q][0], acc[0][0], 0, 0, 0);
        acc[0][1] = __builtin_amdgcn_mfma_f32_16x16x32_bf16(a0, bf[q][1], acc[0][1], 0, 0, 0);
        acc[0][2] = __builtin_amdgcn_mfma_f32_16x16x32_bf16(a0, bf[q][2], acc[0][2], 0, 0, 0);
        acc[1][0] = __builtin_amdgcn_mfma_f32_16x16x32_bf16(a1, bf[q][0], acc[1][0], 0, 0, 0);
        acc[1][1] = __builtin_amdgcn_mfma_f32_16x16x32_bf16(a1, bf[q][1], acc[1][1], 0, 0, 0);
        acc[1][2] = __builtin_amdgcn_mfma_f32_16x16x32_bf16(a1, bf[q][2], acc[1][2], 0, 0, 0);
    }

    // Store Z + per-lane max. C layout: col=lane&15, row=(lane>>4)*4+reg.
    float tmax[3] = {-INFINITY, -INFINITY, -INFINITY};
#pragma unroll
    for (int m = 0; m < 2; ++m) {
#pragma unroll
        for (int r = 0; r < 4; ++r) {
            int p = p0 + pw + m * 16 + ls * 4 + r;
            if (p < PPn) {
                float* zp = Z + ((size_t)b * PPn + p) * Un + lr;
#pragma unroll
                for (int n = 0; n < 3; ++n) {
                    float val = acc[m][n][r];
                    zp[n * 16] = val;
                    tmax[n] = fmaxf(tmax[n], val);
                }
            }
        }
    }

    // Column max: fold the 4 ls-groups, then across the 4 waves via LDS.
#pragma unroll
    for (int n = 0; n < 3; ++n) {
        tmax[n] = fmaxf(tmax[n], __shfl_xor(tmax[n], 16));
        tmax[n] = fmaxf(tmax[n], __shfl_xor(tmax[n], 32));
    }
    float* red = (float*)(smem + RED_OFF);
    if (ls == 0) {
#pragma unroll
        for (int n = 0; n < 3; ++n) red[w * Un + n * 16 + lr] = tmax[n];
    }
    __syncthreads();
    if (t < Un) {
        float m = -INFINITY;
#pragma unroll
        for (int wv = 0; wv < 4; ++wv) m = fmaxf(m, red[wv * Un + t]);
        atomicMax(&Skey[(b / D2n) * Un + t], fkey(m));
    }
}

// Kernel 3: decode monotone keys -> float S, in place.
__global__ void k_decode(unsigned int* __restrict__ Skey) {
    int t = blockIdx.x * blockDim.x + threadIdx.x;
    if (t < S_SIZE) {
        float f = funkey(Skey[t]);
        ((float*)Skey)[t] = f;
    }
}

extern "C" void kernel_launch(void* const* d_in, const int* in_sizes, int n_in,
                              void* d_out, int out_size, void* d_ws, size_t ws_size,
                              hipStream_t stream) {
    const float* X = (const float*)d_in[0];
    const float* P_logit = (const float*)d_in[1];
    const float* Q = (const float*)d_in[2];

    float* S = (float*)d_out;
    float* Rout = S + S_SIZE;
    float* Z = Rout + R_SIZE;
    unsigned short* Rb = (unsigned short*)d_ws;  // 24576 bytes of ws

    k_profile<<<(S_SIZE + 63) / 64, 64, 0, stream>>>(P_logit, Q, Rout, Rb,
                                                     (unsigned int*)d_out);

    dim3 grid(NPT, Bn);
    k_conv<<<grid, 256, 0, stream>>>(X, Rb, Z, (unsigned int*)d_out);

    k_decode<<<(S_SIZE + 255) / 256, 256, 0, stream>>>((unsigned int*)d_out);
}

// Round 5
// 114.504 us; speedup vs baseline: 1.1086x; 1.1086x over previous
//
#include <hip/hip_runtime.h>
#include <math.h>

typedef __attribute__((ext_vector_type(8))) short short8;  // 8 bf16 = 4 VGPRs
typedef __attribute__((ext_vector_type(4))) float f32x4;

// Problem dims
#define D0n 8
#define D1n 12
#define D2n 6
#define Ln 2000
#define An 21
#define KPn 8
#define Un 48
#define PPn 1993              // L - k + 1
#define Bn 576                // D0*D1*D2
#define S_SIZE 4608           // (D0*D1) * U
#define R_SIZE 8064

// Conv tiling: 256 threads = 4 waves, each wave a 32-position x 48-u tile.
#define BPn 128               // positions per block
#define NPT 16                // ceil(1993/128)
#define XROWS 136             // BPn + 8 halo
#define XS_BYTES (XROWS * 64) // 8704: row = 32 bf16 (21 data + 11 zero)
#define RB_BYTES (384 * 64)   // 24576: 8q * 48u rows of 64B
#define BOFF XS_BYTES
#define RED_OFF (XS_BYTES + RB_BYTES)

// XOR swizzle: moves 16B slots within each 512B (8-row) group; bijective,
// preserves 16B alignment. Writer and reader both apply it.
__device__ __forceinline__ int swz(int b) { return b ^ ((b >> 2) & 0x70); }

__device__ __forceinline__ unsigned int fkey(float f) {
    unsigned int u = __float_as_uint(f);
    return (u & 0x80000000u) ? ~u : (u | 0x80000000u);
}
__device__ __forceinline__ float funkey(unsigned int k) {
    return __uint_as_float((k & 0x80000000u) ? (k ^ 0x80000000u) : ~k);
}
__device__ __forceinline__ unsigned short f2bf(float v) {
    unsigned int b = __float_as_uint(v);
    return (unsigned short)((b + 0x7FFFu + ((b >> 16) & 1u)) >> 16);  // RNE
}

#define GLOAD_LDS16(g, l)                                                     \
    __builtin_amdgcn_global_load_lds(                                          \
        (const __attribute__((address_space(1))) void*)(g),                    \
        (__attribute__((address_space(3))) void*)(l), 16, 0, 0)

// Kernel 1: zero S-keys; R = log(max(softmax(P_logit)/Q, eps)) -> fp32 to
// d_out + bf16 alphabet-padded(21->32) pre-swizzled copy to ws (row = q*48+u,
// 64B rows) which k_conv stages verbatim into LDS.
__global__ void k_profile(const float* __restrict__ P_logit,
                          const float* __restrict__ Q,
                          float* __restrict__ Rout,
                          unsigned short* __restrict__ Rb,
                          unsigned int* __restrict__ Skey) {
    int t = blockIdx.x * blockDim.x + threadIdx.x;
    if (t < S_SIZE) Skey[t] = 0u;  // key 0 == identity for monotone-uint max
    if (t >= KPn * Un) return;
    int kp = t / Un, u = t % Un;
    const float* pl = P_logit + kp * (An * Un) + u;
    float v[An];
    float m = -INFINITY;
#pragma unroll
    for (int a = 0; a < An; ++a) { v[a] = pl[a * Un]; m = fmaxf(m, v[a]); }
    float s = 0.f;
#pragma unroll
    for (int a = 0; a < An; ++a) { v[a] = expf(v[a] - m); s += v[a]; }
    float inv = 1.f / s;
    int rowp = kp * Un + u;
#pragma unroll
    for (int a = 0; a < An; ++a) {
        float r = logf(fmaxf(v[a] * inv / Q[a], 1e-6f));
        Rout[(kp * An + a) * Un + u] = r;
        Rb[swz(rowp * 64 + a * 2) >> 1] = f2bf(r);
    }
#pragma unroll
    for (int a = An; a < 32; ++a) Rb[swz(rowp * 64 + a * 2) >> 1] = 0;
}

// Kernel 2: Z[b,p,u] = sum_q sum_a X[b,p+q,a]*R[q*21+a,u], bf16 MFMA.
// B staged once per block into LDS (global_load_lds), hoisted once per wave
// into registers (24 frags = 96 VGPR); q-loop = 2 ds_read_b128 + 6 MFMA.
// NO min-waves launch bound: R4's (256,3) capped VGPR at 64 and spilled bf[].
__global__ __launch_bounds__(256) void k_conv(
        const float* __restrict__ X,
        const unsigned short* __restrict__ Rb,
        float* __restrict__ Z,
        unsigned int* __restrict__ Skey) {
    __shared__ char smem[XS_BYTES + RB_BYTES + 4 * Un * 4];
    const int b = blockIdx.y;
    const int p0 = blockIdx.x * BPn;
    const int t = threadIdx.x;
    const int w = t >> 6;        // wave 0..3
    const int l = t & 63;
    const int lr = l & 15;       // fragment lane row/col
    const int ls = l >> 4;       // k-subchunk / C-row group
    const int pw = w * 32;

    // Issue async B stage (ws copy already bf16+padded+swizzled; linear copy
    // satisfies wave-uniform-base + lane*16 dest rule).
    {
        const uint4* src = (const uint4*)Rb;
        uint4* dst = (uint4*)(smem + BOFF);
#pragma unroll
        for (int i = 0; i < RB_BYTES / 16 / 256; ++i) {  // 6 iters
            int idx = t + i * 256;
            GLOAD_LDS16(src + idx, dst + idx);
        }
    }
    // Zero-fill X slab (b128), then overwrite valid elems as packed pairs.
    {
        uint4 z4 = {0u, 0u, 0u, 0u};
        uint4* xs = (uint4*)smem;
#pragma unroll
        for (int i = 0; i < XS_BYTES / 16 / 256 + 1; ++i) {
            int idx = t + i * 256;
            if (idx < XS_BYTES / 16) xs[idx] = z4;
        }
    }
    __syncthreads();  // zero-fill + B-stage complete
    {
        const int rows_avail = min(XROWS, Ln - p0);
        const int npair = rows_avail * 11;  // 11 bf16-pairs per row
        const float* Xb = X + ((size_t)b * Ln + p0) * An;
        for (int j = t; j < npair; j += 256) {
            int row = j / 11, jj = j - row * 11;
            int a = jj * 2;
            float v0 = Xb[row * An + a];
            float v1 = (a + 1 < An) ? Xb[row * An + a + 1] : 0.f;
            unsigned int pk = (unsigned int)f2bf(v0) |
                              ((unsigned int)f2bf(v1) << 16);
            *(unsigned int*)(smem + swz(row * 64 + a * 2)) = pk;
        }
    }
    __syncthreads();

    // Hoist B-fragments LDS -> registers, once per wave (conflict-free under
    // swizzle: 16 rows x 64B stride spread across bank groups, 2-way = free).
    short8 bf[KPn][3];
#pragma unroll
    for (int q = 0; q < KPn; ++q)
#pragma unroll
        for (int nt = 0; nt < 3; ++nt) {
            int rowp = q * Un + nt * 16 + lr;
            bf[q][nt] = *(const short8*)(smem + BOFF + swz(rowp * 64 + ls * 16));
        }

    f32x4 acc[2][3];
#pragma unroll
    for (int m = 0; m < 2; ++m)
#pragma unroll
        for (int n = 0; n < 3; ++n) acc[m][n] = (f32x4){0.f, 0.f, 0.f, 0.f};

#pragma unroll
    for (int q = 0; q < KPn; ++q) {
        const int ar = pw + q + lr;
        short8 a0 = *(const short8*)(smem + swz(ar * 64 + ls * 16));
        short8 a1 = *(const short8*)(smem + swz((ar + 16) * 64 + ls * 16));
        acc[0][0] = __builtin_amdgcn_mfma_f32_16x16x32_bf16(a0, bf[q][0], acc[0][0], 0, 0, 0);
        acc[0][1] = __builtin_amdgcn_mfma_f32_16x16x32_bf16(a0, bf[q][1], acc[0][1], 0, 0, 0);
        acc[0][2] = __builtin_amdgcn_mfma_f32_16x16x32_bf16(a0, bf[q][2], acc[0][2], 0, 0, 0);
        acc[1][0] = __builtin_amdgcn_mfma_f32_16x16x32_bf16(a1, bf[q][0], acc[1][0], 0, 0, 0);
        acc[1][1] = __builtin_amdgcn_mfma_f32_16x16x32_bf16(a1, bf[q][1], acc[1][1], 0, 0, 0);
        acc[1][2] = __builtin_amdgcn_mfma_f32_16x16x32_bf16(a1, bf[q][2], acc[1][2], 0, 0, 0);
    }

    // Store Z + per-lane max. C layout: col=lane&15, row=(lane>>4)*4+reg.
    float tmax[3] = {-INFINITY, -INFINITY, -INFINITY};
#pragma unroll
    for (int m = 0; m < 2; ++m) {
#pragma unroll
        for (int r = 0; r < 4; ++r) {
            int p = p0 + pw + m * 16 + ls * 4 + r;
            if (p < PPn) {
                float* zp = Z + ((size_t)b * PPn + p) * Un + lr;
#pragma unroll
                for (int n = 0; n < 3; ++n) {
                    float val = acc[m][n][r];
                    zp[n * 16] = val;
                    tmax[n] = fmaxf(tmax[n], val);
                }
            }
        }
    }

    // Column max: fold the 4 ls-groups, then across the 4 waves via LDS.
#pragma unroll
    for (int n = 0; n < 3; ++n) {
        tmax[n] = fmaxf(tmax[n], __shfl_xor(tmax[n], 16));
        tmax[n] = fmaxf(tmax[n], __shfl_xor(tmax[n], 32));
    }
    float* red = (float*)(smem + RED_OFF);
    if (ls == 0) {
#pragma unroll
        for (int n = 0; n < 3; ++n) red[w * Un + n * 16 + lr] = tmax[n];
    }
    __syncthreads();
    if (t < Un) {
        float m = -INFINITY;
#pragma unroll
        for (int wv = 0; wv < 4; ++wv) m = fmaxf(m, red[wv * Un + t]);
        atomicMax(&Skey[(b / D2n) * Un + t], fkey(m));
    }
}

// Kernel 3: decode monotone keys -> float S, in place.
__global__ void k_decode(unsigned int* __restrict__ Skey) {
    int t = blockIdx.x * blockDim.x + threadIdx.x;
    if (t < S_SIZE) {
        float f = funkey(Skey[t]);
        ((float*)Skey)[t] = f;
    }
}

extern "C" void kernel_launch(void* const* d_in, const int* in_sizes, int n_in,
                              void* d_out, int out_size, void* d_ws, size_t ws_size,
                              hipStream_t stream) {
    const float* X = (const float*)d_in[0];
    const float* P_logit = (const float*)d_in[1];
    const float* Q = (const float*)d_in[2];

    float* S = (float*)d_out;
    float* Rout = S + S_SIZE;
    float* Z = Rout + R_SIZE;
    unsigned short* Rb = (unsigned short*)d_ws;  // 24576 bytes of ws

    k_profile<<<(S_SIZE + 63) / 64, 64, 0, stream>>>(P_logit, Q, Rout, Rb,
                                                     (unsigned int*)d_out);

    dim3 grid(NPT, Bn);
    k_conv<<<grid, 256, 0, stream>>>(X, Rb, Z, (unsigned int*)d_out);

    k_decode<<<(S_SIZE + 255) / 256, 256, 0, stream>>>((unsigned int*)d_out);
}

// Round 6
// 88.344 us; speedup vs baseline: 1.4368x; 1.2961x over previous
//
#include <hip/hip_runtime.h>
#include <math.h>

typedef __attribute__((ext_vector_type(8))) short short8;  // 8 bf16 = 4 VGPRs
typedef __attribute__((ext_vector_type(4))) float f32x4;

// Problem dims
#define D0n 8
#define D1n 12
#define D2n 6
#define Ln 2000
#define An 21
#define KPn 8
#define Un 48
#define PPn 1993              // L - k + 1
#define Bn 576                // D0*D1*D2
#define S_SIZE 4608           // (D0*D1) * U
#define R_SIZE 8064

// Conv tiling: 512 threads = 8 waves; each wave: 32 positions x 48 u.
// Each block: 4 tiles of 256 positions (1024 positions), double-buffered X.
#define BPn 256
#define TILES 4
#define XROWS 264              // 256 + 8 halo
#define XBUF_BYTES (XROWS * 64)  // 16896 (512-aligned: 33*512)
#define RB_BYTES (384 * 64)    // 24576
#define BOFF (2 * XBUF_BYTES)
#define RED_OFF (BOFF + RB_BYTES)

// XOR swizzle within each 512B (8-row) group; bijective, 16B-granular.
__device__ __forceinline__ int swz(int b) { return b ^ ((b >> 2) & 0x70); }

__device__ __forceinline__ unsigned int fkey(float f) {
    unsigned int u = __float_as_uint(f);
    return (u & 0x80000000u) ? ~u : (u | 0x80000000u);
}
__device__ __forceinline__ float funkey(unsigned int k) {
    return __uint_as_float((k & 0x80000000u) ? (k ^ 0x80000000u) : ~k);
}
__device__ __forceinline__ unsigned short f2bf(float v) {
    unsigned int b = __float_as_uint(v);
    return (unsigned short)((b + 0x7FFFu + ((b >> 16) & 1u)) >> 16);  // RNE
}

#define GLOAD_LDS16(g, l)                                                     \
    __builtin_amdgcn_global_load_lds(                                          \
        (const __attribute__((address_space(1))) void*)(g),                    \
        (__attribute__((address_space(3))) void*)(l), 16, 0, 0)

// Kernel 1: zero S-keys; R = log(max(softmax(P_logit)/Q, eps)) -> fp32 to
// d_out + bf16 padded(21->32) pre-swizzled copy to ws (row = q*48+u, 64B
// rows) which k_conv stages verbatim via global_load_lds.
__global__ void k_profile(const float* __restrict__ P_logit,
                          const float* __restrict__ Q,
                          float* __restrict__ Rout,
                          unsigned short* __restrict__ Rb,
                          unsigned int* __restrict__ Skey) {
    int t = blockIdx.x * blockDim.x + threadIdx.x;
    if (t < S_SIZE) Skey[t] = 0u;
    if (t >= KPn * Un) return;
    int kp = t / Un, u = t % Un;
    const float* pl = P_logit + kp * (An * Un) + u;
    float v[An];
    float m = -INFINITY;
#pragma unroll
    for (int a = 0; a < An; ++a) { v[a] = pl[a * Un]; m = fmaxf(m, v[a]); }
    float s = 0.f;
#pragma unroll
    for (int a = 0; a < An; ++a) { v[a] = expf(v[a] - m); s += v[a]; }
    float inv = 1.f / s;
    int rowp = kp * Un + u;
#pragma unroll
    for (int a = 0; a < An; ++a) {
        float r = logf(fmaxf(v[a] * inv / Q[a], 1e-6f));
        Rout[(kp * An + a) * Un + u] = r;
        Rb[swz(rowp * 64 + a * 2) >> 1] = f2bf(r);
    }
#pragma unroll
    for (int a = An; a < 32; ++a) Rb[swz(rowp * 64 + a * 2) >> 1] = 0;
}

// Convert a staged float4 (4 consecutive flat X elems) into swizzled bf16 LDS.
__device__ __forceinline__ void xwrite4(char* xbase, int idx, f32x4 g) {
    int fi = idx * 4;
    int row = fi / An;          // magic-mul
    int a = fi - row * An;
#pragma unroll
    for (int e = 0; e < 4; ++e) {
        *(unsigned short*)(xbase + swz(row * 64 + a * 2)) = f2bf(g[e]);
        ++a;
        if (a == An) { a = 0; ++row; }
    }
}

// Kernel 2: Z[b,p,u] = sum_q sum_a X[b,p+q,a]*R[q*21+a,u], bf16 MFMA.
// Swapped operands: mfma(R_frag, X_frag) -> lane holds 4 consecutive u at
// fixed p -> dwordx4 Z stores. B in LDS (re-read per q; keeps VGPR <= 128).
__global__ __launch_bounds__(512) void k_conv(
        const float* __restrict__ X,
        const unsigned short* __restrict__ Rb,
        float* __restrict__ Z,
        unsigned int* __restrict__ Skey) {
    __shared__ char smem[2 * XBUF_BYTES + RB_BYTES + 8 * Un * 4];
    const int b = blockIdx.y;
    const int base_p = blockIdx.x * (TILES * BPn);   // 0 or 1024
    const int t = threadIdx.x;
    const int w = t >> 6;
    const int l = t & 63;
    const int lr = l & 15;
    const int ls = l >> 4;
    const int pw = w * 32;

    // ---- Prologue ----
    // Stage B (async, linear: wave-uniform base + lane*16 holds).
    {
        const uint4* src = (const uint4*)Rb;
        uint4* dst = (uint4*)(smem + BOFF);
#pragma unroll
        for (int i = 0; i < RB_BYTES / 16 / 512; ++i) {  // 3
            int idx = t + i * 512;
            GLOAD_LDS16(src + idx, dst + idx);
        }
    }
    // Zero-fill BOTH X buffers (pad columns + short-tile rows stay zero or
    // finite-garbage; garbage rows only feed masked p >= PPn).
    {
        uint4 z4 = {0u, 0u, 0u, 0u};
        uint4* xs = (uint4*)smem;
        for (int i = t; i < 2 * XBUF_BYTES / 16; i += 512) xs[i] = z4;
    }
    // Load tile 0 into regs.
    const float* Xb = X + ((size_t)b * Ln + base_p) * An;
    f32x4 g[3];
    int n4_0;
    {
        int rows = min(XROWS, Ln - base_p);
        n4_0 = rows * An / 4;
        const f32x4* src = (const f32x4*)Xb;
#pragma unroll
        for (int i = 0; i < 3; ++i) {
            int idx = t + i * 512;
            g[i] = (idx < n4_0) ? src[idx] : (f32x4){0.f, 0.f, 0.f, 0.f};
        }
    }
    __syncthreads();  // zero-fill visible (B-stage also drained here)
    // Write tile 0 into buf0.
#pragma unroll
    for (int i = 0; i < 3; ++i) {
        int idx = t + i * 512;
        if (idx < n4_0) xwrite4((char*)smem, idx, g[i]);
    }
    __syncthreads();

    float smax[3][4];
#pragma unroll
    for (int nu = 0; nu < 3; ++nu)
#pragma unroll
        for (int r = 0; r < 4; ++r) smax[nu][r] = -INFINITY;

    // ---- Tile loop ----
    int n4_next = 0;
    for (int tt = 0; tt < TILES; ++tt) {
        char* xb = (char*)smem + (tt & 1) * XBUF_BYTES;
        const int tp0 = base_p + tt * BPn;

        // Issue next tile's global loads early (drained by barrier below).
        if (tt + 1 < TILES) {
            int np0 = base_p + (tt + 1) * BPn;
            int rows = min(XROWS, Ln - np0);
            n4_next = rows * An / 4;
            const f32x4* src = (const f32x4*)(X + ((size_t)b * Ln + np0) * An);
#pragma unroll
            for (int i = 0; i < 3; ++i) {
                int idx = t + i * 512;
                g[i] = (idx < n4_next) ? src[idx] : (f32x4){0.f, 0.f, 0.f, 0.f};
            }
        }

        // q-loop: A-operand = R rows (u), B-operand = X rows (positions).
        f32x4 acc[3][2];
#pragma unroll
        for (int nu = 0; nu < 3; ++nu)
#pragma unroll
            for (int np = 0; np < 2; ++np) acc[nu][np] = (f32x4){0.f, 0.f, 0.f, 0.f};

#pragma unroll
        for (int q = 0; q < KPn; ++q) {
            const int rr = q * Un + lr;
            short8 rf0 = *(const short8*)(smem + BOFF + swz(rr * 64 + ls * 16));
            short8 rf1 = *(const short8*)(smem + BOFF + swz((rr + 16) * 64 + ls * 16));
            short8 rf2 = *(const short8*)(smem + BOFF + swz((rr + 32) * 64 + ls * 16));
            const int xr = pw + q + lr;
            short8 xf0 = *(const short8*)(xb + swz(xr * 64 + ls * 16));
            short8 xf1 = *(const short8*)(xb + swz((xr + 16) * 64 + ls * 16));
            acc[0][0] = __builtin_amdgcn_mfma_f32_16x16x32_bf16(rf0, xf0, acc[0][0], 0, 0, 0);
            acc[0][1] = __builtin_amdgcn_mfma_f32_16x16x32_bf16(rf0, xf1, acc[0][1], 0, 0, 0);
            acc[1][0] = __builtin_amdgcn_mfma_f32_16x16x32_bf16(rf1, xf0, acc[1][0], 0, 0, 0);
            acc[1][1] = __builtin_amdgcn_mfma_f32_16x16x32_bf16(rf1, xf1, acc[1][1], 0, 0, 0);
            acc[2][0] = __builtin_amdgcn_mfma_f32_16x16x32_bf16(rf2, xf0, acc[2][0], 0, 0, 0);
            acc[2][1] = __builtin_amdgcn_mfma_f32_16x16x32_bf16(rf2, xf1, acc[2][1], 0, 0, 0);
        }

        // Z stores: lane owns Z[p = tp0+pw+np*16+lr][u = nu*16+ls*4 .. +3].
#pragma unroll
        for (int np = 0; np < 2; ++np) {
            int p = tp0 + pw + np * 16 + lr;
            if (p < PPn) {
                float* zp = Z + ((size_t)b * PPn + p) * Un + ls * 4;
#pragma unroll
                for (int nu = 0; nu < 3; ++nu) {
                    *(f32x4*)(zp + nu * 16) = acc[nu][np];
#pragma unroll
                    for (int r = 0; r < 4; ++r)
                        smax[nu][r] = fmaxf(smax[nu][r], acc[nu][np][r]);
                }
            }
        }

        if (tt + 1 < TILES) {
            __syncthreads();  // all waves done reading buf[(tt+1)&1]'s old data
            char* xn = (char*)smem + ((tt + 1) & 1) * XBUF_BYTES;
#pragma unroll
            for (int i = 0; i < 3; ++i) {
                int idx = t + i * 512;
                if (idx < n4_next) xwrite4(xn, idx, g[i]);
            }
            __syncthreads();  // next buffer ready
        }
    }

    // ---- S reduction: max over positions = over lr lanes, then waves ----
    float* red = (float*)(smem + RED_OFF);
#pragma unroll
    for (int nu = 0; nu < 3; ++nu)
#pragma unroll
        for (int r = 0; r < 4; ++r) {
            float v = smax[nu][r];
            v = fmaxf(v, __shfl_xor(v, 1));
            v = fmaxf(v, __shfl_xor(v, 2));
            v = fmaxf(v, __shfl_xor(v, 4));
            v = fmaxf(v, __shfl_xor(v, 8));
            if (lr == 0) red[w * Un + nu * 16 + ls * 4 + r] = v;
        }
    __syncthreads();
    if (t < Un) {
        float m = -INFINITY;
#pragma unroll
        for (int wv = 0; wv < 8; ++wv) m = fmaxf(m, red[wv * Un + t]);
        atomicMax(&Skey[(b / D2n) * Un + t], fkey(m));
    }
}

// Kernel 3: decode monotone keys -> float S, in place.
__global__ void k_decode(unsigned int* __restrict__ Skey) {
    int t = blockIdx.x * blockDim.x + threadIdx.x;
    if (t < S_SIZE) {
        float f = funkey(Skey[t]);
        ((float*)Skey)[t] = f;
    }
}

extern "C" void kernel_launch(void* const* d_in, const int* in_sizes, int n_in,
                              void* d_out, int out_size, void* d_ws, size_t ws_size,
                              hipStream_t stream) {
    const float* X = (const float*)d_in[0];
    const float* P_logit = (const float*)d_in[1];
    const float* Q = (const float*)d_in[2];

    float* S = (float*)d_out;
    float* Rout = S + S_SIZE;
    float* Z = Rout + R_SIZE;
    unsigned short* Rb = (unsigned short*)d_ws;  // 24576 bytes of ws

    k_profile<<<(S_SIZE + 63) / 64, 64, 0, stream>>>(P_logit, Q, Rout, Rb,
                                                     (unsigned int*)d_out);

    dim3 grid(2, Bn);  // 2 x 4 tiles of 256 positions covers 2048 >= 1993
    k_conv<<<grid, 512, 0, stream>>>(X, Rb, Z, (unsigned int*)d_out);

    k_decode<<<(S_SIZE + 255) / 256, 256, 0, stream>>>((unsigned int*)d_out);
}

// Round 8
// 82.527 us; speedup vs baseline: 1.5381x; 1.0705x over previous
//
#include <hip/hip_runtime.h>
#include <math.h>

typedef __attribute__((ext_vector_type(8))) short short8;  // 8 bf16 = 4 VGPRs
typedef __attribute__((ext_vector_type(4))) float f32x4;

// Problem dims
#define D0n 8
#define D1n 12
#define D2n 6
#define Ln 2000
#define An 21
#define KPn 8
#define Un 48
#define PPn 1993              // L - k + 1
#define Bn 576                // D0*D1*D2
#define S_SIZE 4608           // (D0*D1) * U
#define R_SIZE 8064

// Conv tiling: 512 threads = 8 waves; wave = 32 positions x 48 u.
// Block: 2 tiles of 256 positions; grid (4, 576) = 2304 blocks = 9/CU exact.
#define BPn 256
#define TILES 2
#define NBX 4
#define XROWS 264              // 256 + halo, even
#define XBUF_BYTES (XROWS * 64)  // 16896
#define RB_BYTES (384 * 64)    // 24576
#define BOFF (2 * XBUF_BYTES)
#define RED_OFF (BOFF + RB_BYTES)

// XOR swizzle within each 512B (8-row) group; bijective, 16B-granular.
__device__ __forceinline__ int swz(int b) { return b ^ ((b >> 2) & 0x70); }

__device__ __forceinline__ unsigned int fkey(float f) {
    unsigned int u = __float_as_uint(f);
    return (u & 0x80000000u) ? ~u : (u | 0x80000000u);
}
__device__ __forceinline__ float funkey(unsigned int k) {
    return __uint_as_float((k & 0x80000000u) ? (k ^ 0x80000000u) : ~k);
}
__device__ __forceinline__ unsigned short f2bf(float v) {
    unsigned int b = __float_as_uint(v);
    return (unsigned short)((b + 0x7FFFu + ((b >> 16) & 1u)) >> 16);  // RNE
}

#define GLOAD_LDS16(g, l)                                                     \
    __builtin_amdgcn_global_load_lds(                                          \
        (const __attribute__((address_space(1))) void*)(g),                    \
        (__attribute__((address_space(3))) void*)(l), 16, 0, 0)

// lgkm-only wait + raw barrier: do NOT drain vmcnt (Z-stores stay in flight
// across tile boundaries; they have no readers).
#define TILE_BARRIER()                                                        \
    do {                                                                      \
        asm volatile("s_waitcnt lgkmcnt(0)" ::: "memory");                    \
        __builtin_amdgcn_s_barrier();                                         \
        asm volatile("" ::: "memory");                                        \
    } while (0)

// Kernel 1: zero S-keys; R = log(max(softmax(P_logit)/Q, eps)) -> fp32 to
// d_out + bf16 padded(21->32) pre-swizzled copy to ws (row = q*48+u, 64B
// rows) staged verbatim by k_conv via global_load_lds.
__global__ void k_profile(const float* __restrict__ P_logit,
                          const float* __restrict__ Q,
                          float* __restrict__ Rout,
                          unsigned short* __restrict__ Rb,
                          unsigned int* __restrict__ Skey) {
    int t = blockIdx.x * blockDim.x + threadIdx.x;
    if (t < S_SIZE) Skey[t] = 0u;
    if (t >= KPn * Un) return;
    int kp = t / Un, u = t % Un;
    const float* pl = P_logit + kp * (An * Un) + u;
    float v[An];
    float m = -INFINITY;
#pragma unroll
    for (int a = 0; a < An; ++a) { v[a] = pl[a * Un]; m = fmaxf(m, v[a]); }
    float s = 0.f;
#pragma unroll
    for (int a = 0; a < An; ++a) { v[a] = expf(v[a] - m); s += v[a]; }
    float inv = 1.f / s;
    int rowp = kp * Un + u;
#pragma unroll
    for (int a = 0; a < An; ++a) {
        float r = logf(fmaxf(v[a] * inv / Q[a], 1e-6f));
        Rout[(kp * An + a) * Un + u] = r;
        Rb[swz(rowp * 64 + a * 2) >> 1] = f2bf(r);
    }
#pragma unroll
    for (int a = An; a < 32; ++a) Rb[swz(rowp * 64 + a * 2) >> 1] = 0;
}

// Convert one staged float4 (4 consecutive flat X elems) to swizzled bf16 LDS.
__device__ __forceinline__ void xwrite4(char* xbase, int idx, f32x4 g) {
    int fi = idx * 4;
    int row = fi / An;
    int a = fi - row * An;
#pragma unroll
    for (int e = 0; e < 4; ++e) {
        *(unsigned short*)(xbase + swz(row * 64 + a * 2)) = f2bf(g[e]);
        ++a;
        if (a == An) { a = 0; ++row; }
    }
}

__device__ __forceinline__ void xload(const float* __restrict__ X, int b,
                                      int tp0, int t, f32x4 g[3], int& n4) {
    int rows = min(XROWS, Ln - tp0);
    n4 = rows * An / 4;  // rows in {264, 208} -> always divisible by 4
    const f32x4* src = (const f32x4*)(X + ((size_t)b * Ln + tp0) * An);
#pragma unroll
    for (int i = 0; i < 3; ++i) {
        int idx = t + i * 512;
        g[i] = (idx < n4) ? src[idx] : (f32x4){0.f, 0.f, 0.f, 0.f};
    }
}

__device__ __forceinline__ void xstore(char* xbase, int t, const f32x4 g[3],
                                       int n4) {
#pragma unroll
    for (int i = 0; i < 3; ++i) {
        int idx = t + i * 512;
        if (idx < n4) xwrite4(xbase, idx, g[i]);
    }
}

// q-loop: A-operand = R rows (u axis), B-operand = X rows (positions).
__device__ __forceinline__ void qloop8(const char* smem, const char* xb,
                                       int lr, int ls, int pw,
                                       f32x4 acc[3][2]) {
#pragma unroll
    for (int q = 0; q < KPn; ++q) {
        const int rr = q * Un + lr;
        short8 rf0 = *(const short8*)(smem + BOFF + swz(rr * 64 + ls * 16));
        short8 rf1 = *(const short8*)(smem + BOFF + swz((rr + 16) * 64 + ls * 16));
        short8 rf2 = *(const short8*)(smem + BOFF + swz((rr + 32) * 64 + ls * 16));
        const int xr = pw + q + lr;
        short8 xf0 = *(const short8*)(xb + swz(xr * 64 + ls * 16));
        short8 xf1 = *(const short8*)(xb + swz((xr + 16) * 64 + ls * 16));
        acc[0][0] = __builtin_amdgcn_mfma_f32_16x16x32_bf16(rf0, xf0, acc[0][0], 0, 0, 0);
        acc[0][1] = __builtin_amdgcn_mfma_f32_16x16x32_bf16(rf0, xf1, acc[0][1], 0, 0, 0);
        acc[1][0] = __builtin_amdgcn_mfma_f32_16x16x32_bf16(rf1, xf0, acc[1][0], 0, 0, 0);
        acc[1][1] = __builtin_amdgcn_mfma_f32_16x16x32_bf16(rf1, xf1, acc[1][1], 0, 0, 0);
        acc[2][0] = __builtin_amdgcn_mfma_f32_16x16x32_bf16(rf2, xf0, acc[2][0], 0, 0, 0);
        acc[2][1] = __builtin_amdgcn_mfma_f32_16x16x32_bf16(rf2, xf1, acc[2][1], 0, 0, 0);
    }
}

// Z stores: lane owns Z[p = tp0+pw+np*16+lr][u = ls*4 + nu*16 .. +3].
__device__ __forceinline__ void store_tile(float* __restrict__ Z, int b,
                                           int tp0, int pw, int lr, int ls,
                                           const f32x4 acc[3][2],
                                           float smax[3][4]) {
#pragma unroll
    for (int np = 0; np < 2; ++np) {
        int p = tp0 + pw + np * 16 + lr;
        if (p < PPn) {
            float* zp = Z + ((size_t)b * PPn + p) * Un + ls * 4;
#pragma unroll
            for (int nu = 0; nu < 3; ++nu) {
                *(f32x4*)(zp + nu * 16) = acc[nu][np];
#pragma unroll
                for (int r = 0; r < 4; ++r)
                    smax[nu][r] = fmaxf(smax[nu][r], acc[nu][np][r]);
            }
        }
    }
}

__global__ __launch_bounds__(512, 4) void k_conv(
        const float* __restrict__ X,
        const unsigned short* __restrict__ Rb,
        float* __restrict__ Z,
        unsigned int* __restrict__ Skey) {
    __shared__ char smem[RED_OFF + 8 * Un * 4];
    const int b = blockIdx.y;
    const int base_p = blockIdx.x * (TILES * BPn);
    const int t = threadIdx.x;
    const int w = t >> 6;
    const int l = t & 63;
    const int lr = l & 15;
    const int ls = l >> 4;
    const int pw = w * 32;

    // ---- Prologue ----
    {   // Stage B (async; ws copy is linear bf16+padded+swizzled).
        const uint4* src = (const uint4*)Rb;
        uint4* dst = (uint4*)(smem + BOFF);
#pragma unroll
        for (int i = 0; i < RB_BYTES / 16 / 512; ++i) {  // 3
            int idx = t + i * 512;
            GLOAD_LDS16(src + idx, dst + idx);
        }
    }
    {   // Zero-fill BOTH X buffers (pad columns stay zero forever).
        uint4 z4 = {0u, 0u, 0u, 0u};
        uint4* xs = (uint4*)smem;
        for (int i = t; i < 2 * XBUF_BYTES / 16; i += 512) xs[i] = z4;
    }
    f32x4 g[3];
    int n4;
    xload(X, b, base_p, t, g, n4);
    __syncthreads();  // full drain once: gload_lds B-stage + zero-fill
    xstore((char*)smem, t, g, n4);
    TILE_BARRIER();   // buf0 published (lgkm only)

    float smax[3][4];
#pragma unroll
    for (int nu = 0; nu < 3; ++nu)
#pragma unroll
        for (int r = 0; r < 4; ++r) smax[nu][r] = -INFINITY;

    f32x4 acc[3][2];

    // ---- Tile 0 ----
    xload(X, b, base_p + BPn, t, g, n4);  // prefetch tile 1
#pragma unroll
    for (int nu = 0; nu < 3; ++nu)
#pragma unroll
        for (int np = 0; np < 2; ++np) acc[nu][np] = (f32x4){0.f, 0.f, 0.f, 0.f};
    qloop8((const char*)smem, (const char*)smem, lr, ls, pw, acc);
    xstore((char*)smem + XBUF_BYTES, t, g, n4);   // stage tile 1 -> buf1
    store_tile(Z, b, base_p, pw, lr, ls, acc, smax);
    TILE_BARRIER();   // buf1 published; Z-stores remain in flight

    // ---- Tile 1 ----
#pragma unroll
    for (int nu = 0; nu < 3; ++nu)
#pragma unroll
        for (int np = 0; np < 2; ++np) acc[nu][np] = (f32x4){0.f, 0.f, 0.f, 0.f};
    qloop8((const char*)smem, (const char*)smem + XBUF_BYTES, lr, ls, pw, acc);
    store_tile(Z, b, base_p + BPn, pw, lr, ls, acc, smax);

    // ---- S reduction: max over positions (lr lanes), then waves ----
    float* red = (float*)(smem + RED_OFF);
#pragma unroll
    for (int nu = 0; nu < 3; ++nu)
#pragma unroll
        for (int r = 0; r < 4; ++r) {
            float v = smax[nu][r];
            v = fmaxf(v, __shfl_xor(v, 1));
            v = fmaxf(v, __shfl_xor(v, 2));
            v = fmaxf(v, __shfl_xor(v, 4));
            v = fmaxf(v, __shfl_xor(v, 8));
            if (lr == 0) red[w * Un + nu * 16 + ls * 4 + r] = v;
        }
    __syncthreads();
    if (t < Un) {
        float m = -INFINITY;
#pragma unroll
        for (int wv = 0; wv < 8; ++wv) m = fmaxf(m, red[wv * Un + t]);
        atomicMax(&Skey[(b / D2n) * Un + t], fkey(m));
    }
}

// Kernel 3: decode monotone keys -> float S, in place.
__global__ void k_decode(unsigned int* __restrict__ Skey) {
    int t = blockIdx.x * blockDim.x + threadIdx.x;
    if (t < S_SIZE) {
        float f = funkey(Skey[t]);
        ((float*)Skey)[t] = f;
    }
}

extern "C" void kernel_launch(void* const* d_in, const int* in_sizes, int n_in,
                              void* d_out, int out_size, void* d_ws, size_t ws_size,
                              hipStream_t stream) {
    const float* X = (const float*)d_in[0];
    const float* P_logit = (const float*)d_in[1];
    const float* Q = (const float*)d_in[2];

    float* S = (float*)d_out;
    float* Rout = S + S_SIZE;
    float* Z = Rout + R_SIZE;
    unsigned short* Rb = (unsigned short*)d_ws;  // 24576 bytes of ws

    k_profile<<<(S_SIZE + 63) / 64, 64, 0, stream>>>(P_logit, Q, Rout, Rb,
                                                     (unsigned int*)d_out);

    dim3 grid(NBX, Bn);  // 4 x 2 tiles x 256 positions = 2048 >= 1993
    k_conv<<<grid, 512, 0, stream>>>(X, Rb, Z, (unsigned int*)d_out);

    k_decode<<<(S_SIZE + 255) / 256, 256, 0, stream>>>((unsigned int*)d_out);
}